// Round 6
// baseline (1200.925 us; speedup 1.0000x reference)
//
#include <hip/hip_runtime.h>

// Problem constants (fixed by reference setup_inputs)
#define NB 32
#define NC 128
#define NH 63
#define NW 63
#define HW (NH*NW)       // 3969
#define OH 30            // (63-5)/2+1
#define OW 30
#define SEGW 19          // band columns per segment (8 tiles: x0=0..14 -> cols 0..18)
#define POSN (5*SEGW)    // 95 band positions
#define CCH 16           // channels per chunk
#define NCHUNK (NC/CCH)  // 8
#define NSEG 4
#define NBLK (NB*OH*NSEG)   // 3840

__global__ void init_tops(float* tops) {
    if (threadIdx.x < NB) tops[threadIdx.x] = 0.0f;
}

// Band layout: 16-float (64B) rows, granule-swizzled so that 8 consecutive pos
// cover all 8 bank-granule slots exactly once: slot = (c4 + (pos>>1)) & 3.
__device__ __forceinline__ int swz_f4(int pos, int c4) {
    return pos * CCH + (((c4 + (pos >> 1)) & 3) << 2);
}

__global__ __launch_bounds__(128, 8) void seg_kernel(const float* __restrict__ f,
                                                     float* __restrict__ tops) {
    // XCD-chunked swizzle (bijective: 3840 = 8*480); consecutive logical blocks
    // = same strip's segments then adjacent strips -> L2 reuse within an XCD.
    const int lb    = (blockIdx.x & 7) * (NBLK / 8) + (blockIdx.x >> 3);
    const int strip = lb >> 2;           // (b, oi)
    const int g     = lb & 3;            // segment: tiles 8g..8g+7
    const int b     = strip / OH;
    const int oi    = strip % OH;
    const int y0    = oi * 2;
    const int xlo   = 16 * g;
    const int t     = threadIdx.x;

    __shared__ __align__(16) float band[POSN * CCH];   // 6.08 KB
    __shared__ float ssum[8 * 25];
    __shared__ float snorm[8 * 25];
    __shared__ float smax[8];

    for (int u = t; u < 8 * 25; u += 128) ssum[u] = 0.0f;

    // ---- staging geometry: thread t<95 owns band position t (16 channels) ----
    const int  spos = t;
    const int  sr   = spos / SEGW;
    const int  sxx  = spos % SEGW;
    const bool svalid = (t < POSN) && (xlo + sxx < NW);
    const float* gp = f + (size_t)b * NC * HW + (size_t)(y0 + (svalid ? sr : 0)) * NW
                        + xlo + (svalid ? sxx : 0);

    // ---- gram geometry: thread t<120 owns (tile 0..7, row-pair 0..14) ----
    const int tl = t / 15;
    const int pr = t % 15;
    int r1 = 0, rem = pr;
    while (rem >= 5 - r1) { rem -= 5 - r1; ++r1; }
    const int r2 = r1 + rem;             // r1 <= r2
    const bool tvalid = (t < 120) && (8 * g + tl < OH);
    const int x0loc = 2 * tl;
    const int posA  = r1 * SEGW + x0loc;
    const int posB  = r2 * SEGW + x0loc;

    float acc[25];
    #pragma unroll
    for (int k = 0; k < 25; ++k) acc[k] = 0.0f;

    #pragma unroll 1
    for (int ch = 0; ch < NCHUNK; ++ch) {
        __syncthreads();                 // previous chunk consumed (orders ssum zeroing too)
        if (svalid) {
            float rg[16];
            #pragma unroll
            for (int k = 0; k < 16; ++k)
                rg[k] = gp[(size_t)(ch * CCH + k) * HW];   // k*HW compile-time
            #pragma unroll
            for (int c4 = 0; c4 < 4; ++c4) {
                const float4 v = {rg[4 * c4], rg[4 * c4 + 1], rg[4 * c4 + 2], rg[4 * c4 + 3]};
                *(float4*)&band[swz_f4(spos, c4)] = v;
            }
        }
        __syncthreads();                 // band ready
        if (tvalid) {
            #pragma unroll
            for (int c4 = 0; c4 < 4; ++c4) {
                float4 av[5];
                #pragma unroll
                for (int i = 0; i < 5; ++i)
                    av[i] = *(const float4*)&band[swz_f4(posA + i, c4)];
                #pragma unroll
                for (int j = 0; j < 5; ++j) {
                    const float4 bv = *(const float4*)&band[swz_f4(posB + j, c4)];
                    #pragma unroll
                    for (int i = 0; i < 5; ++i) {
                        acc[i * 5 + j] = fmaf(av[i].x, bv.x, acc[i * 5 + j]);
                        acc[i * 5 + j] = fmaf(av[i].y, bv.y, acc[i * 5 + j]);
                        acc[i * 5 + j] = fmaf(av[i].z, bv.z, acc[i * 5 + j]);
                        acc[i * 5 + j] = fmaf(av[i].w, bv.w, acc[i * 5 + j]);
                    }
                }
            }
        }
    }

    // ---- norms from diagonal blocks (exact fp32) ----
    if (tvalid && r1 == r2) {
        #pragma unroll
        for (int i = 0; i < 5; ++i)
            snorm[tl * 25 + r1 * 5 + i] = sqrtf(acc[i * 5 + i]);
    }
    __syncthreads();

    // ---- cosine partial row-sums via LDS atomics ----
    if (tvalid) {
        float n1[5], n2[5];
        #pragma unroll
        for (int i = 0; i < 5; ++i) {
            n1[i] = snorm[tl * 25 + r1 * 5 + i];
            n2[i] = snorm[tl * 25 + r2 * 5 + i];
        }
        float rowp[5] = {0, 0, 0, 0, 0}, colp[5] = {0, 0, 0, 0, 0};
        #pragma unroll
        for (int i = 0; i < 5; ++i)
            #pragma unroll
            for (int j = 0; j < 5; ++j) {
                const float denom = fmaxf(n1[i] * n2[j], 1e-6f);
                const float cv = 1.0f - acc[i * 5 + j] / denom;
                rowp[i] += cv;
                if (r1 != r2) colp[j] += cv;
            }
        #pragma unroll
        for (int i = 0; i < 5; ++i) atomicAdd(&ssum[tl * 25 + r1 * 5 + i], rowp[i]);
        if (r1 != r2) {
            #pragma unroll
            for (int j = 0; j < 5; ++j) atomicAdd(&ssum[tl * 25 + r2 * 5 + j], colp[j]);
        }
    }
    __syncthreads();

    // ---- per-tile max of mean, then segment max -> per-b atomic ----
    if (t < 8) {
        float m = -1e30f;
        #pragma unroll
        for (int p = 0; p < 25; ++p) m = fmaxf(m, ssum[t * 25 + p]);
        smax[t] = (8 * g + t < OH) ? m * (1.0f / 25.0f) : -1e30f;
    }
    __syncthreads();
    if (t == 0) {
        float m = smax[0];
        #pragma unroll
        for (int i = 1; i < 8; ++i) m = fmaxf(m, smax[i]);
        m = fmaxf(m, 0.0f);              // keep int-punned atomicMax valid
        atomicMax((int*)&tops[b], __float_as_int(m));
    }
}

__global__ void finalize(const float* __restrict__ tops,
                         const int* __restrict__ label,
                         float* __restrict__ out) {
    if (threadIdx.x == 0) {
        float fs = 0.0f, rs = 0.0f, fc = 0.0f, rc = 0.0f;
        for (int b = 0; b < NB; ++b) {
            const float tb = tops[b];
            const float lbv = (float)label[b];
            fs += tb * lbv;          fc += lbv;
            rs += tb * (1.0f - lbv); rc += (1.0f - lbv);
        }
        const float loss = 1.0f - fs / fc + rs / rc;
        out[0] = fmaxf(loss, 0.0f);
    }
}

extern "C" void kernel_launch(void* const* d_in, const int* in_sizes, int n_in,
                              void* d_out, int out_size, void* d_ws, size_t ws_size,
                              hipStream_t stream) {
    const float* feature = (const float*)d_in[0];
    const int* label     = (const int*)d_in[1];
    float* out  = (float*)d_out;
    float* tops = (float*)d_ws;   // 32 floats of scratch

    init_tops<<<1, 64, 0, stream>>>(tops);
    seg_kernel<<<NBLK, 128, 0, stream>>>(feature, tops);
    finalize<<<1, 64, 0, stream>>>(tops, label, out);
}

// Round 7
// 80.913 us; speedup vs baseline: 14.8421x; 14.8421x over previous
//
#include <hip/hip_runtime.h>

// Problem constants (fixed by reference setup_inputs)
#define NB 32
#define NC 128
#define NH 63
#define NW 63
#define HW (NH*NW)       // 3969
#define OH 30            // (63-5)/2+1
#define OW 30
#define NPOS (5*NW)      // 315 band positions per strip
#define NTILE 30
#define NITEM (NTILE*25) // 750 (tile, p) items
#define NTHR 384
#define NSTRIP (NB*OH)   // 960

// Band row = 16 floats (64B); granule swizzle spreads the 4 float4-slots so
// consecutive positions rotate bank-granules: slot = (c4 + (pos>>1)) & 3.
__device__ __forceinline__ int bnd(int pos, int c4) {
    return pos * 16 + (((c4 + (pos >> 1)) & 3) << 2);
}

__global__ void init_tops(float* tops) {
    if (threadIdx.x < NB) tops[threadIdx.x] = 0.0f;
}

// s[p] = 1 - (1/25) * e_p . S,  e = f/||f||,  S = sum of the tile's 25 e-vectors.
__global__ __launch_bounds__(NTHR, 8) void strip_kernel(const float* __restrict__ f,
                                                        float* __restrict__ tops) {
    // XCD-chunked swizzle (bijective: 960 = 8*120): adjacent strips share 3/5 rows.
    const int lb = (blockIdx.x & 7) * (NSTRIP / 8) + (blockIdx.x >> 3);
    const int b  = lb / OH;
    const int oi = lb % OH;
    const int y0 = oi * 2;
    const int t  = threadIdx.x;

    __shared__ __align__(16) float band[NPOS * 16];   // 20.2 KB, normalized chunk
    __shared__ __align__(16) float Sl[NTILE * 16];    // per-tile S (chunk slice)
    __shared__ float wmax[NTHR / 64];

    // ---- staging geometry: thread t<315 owns band position t = (sr, sx) ----
    const bool sval = t < NPOS;
    const int  sr = sval ? t / 63 : 0;
    const int  sx = sval ? t % 63 : 0;
    const float* gp = f + (size_t)b * NC * HW + (size_t)(y0 + sr) * NW + sx;

    // ---- pass 1: per-position sum of squares over all 128 channels (registers) ----
    float sumsq = 0.0f;
    if (sval) {
        const float* p = gp;
        #pragma unroll 16
        for (int c = 0; c < NC; ++c) { const float v = *p; p += HW; sumsq = fmaf(v, v, sumsq); }
    }
    const float inv = (sumsq > 0.0f) ? rsqrtf(sumsq) : 0.0f;

    // ---- dot geometry: thread t<375 owns items 2t, 2t+1 (usually same tile) ----
    const bool dval  = t < (NITEM / 2);
    const int  it0   = 2 * t, it1 = 2 * t + 1;
    const int  tile0 = it0 / 25, p0 = it0 % 25;
    const int  tile1 = it1 / 25, p1 = it1 % 25;
    const int  pos0  = (p0 / 5) * NW + 2 * tile0 + (p0 % 5);
    const int  pos1  = (p1 / 5) * NW + 2 * tile1 + (p1 % 5);
    float acc0 = 0.0f, acc1 = 0.0f;

    // ---- pass 2: 8 channel-chunks of 16 ----
    #pragma unroll 1
    for (int ch = 0; ch < 8; ++ch) {
        __syncthreads();                       // prev chunk's dots done
        if (sval) {
            const float* p = gp + (size_t)(ch * 16) * HW;
            float v[16];
            #pragma unroll
            for (int k = 0; k < 16; ++k) { v[k] = *p; p += HW; }
            #pragma unroll
            for (int c4 = 0; c4 < 4; ++c4) {
                const float4 e = {v[4*c4] * inv, v[4*c4+1] * inv,
                                  v[4*c4+2] * inv, v[4*c4+3] * inv};
                *(float4*)&band[bnd(t, c4)] = e;
            }
        }
        __syncthreads();                       // band ready
        if (t < NTILE * 4) {                   // per-tile window sum S
            const int tl = t >> 2, c4 = t & 3;
            float4 s = {0.0f, 0.0f, 0.0f, 0.0f};
            #pragma unroll
            for (int r = 0; r < 5; ++r)
                #pragma unroll
                for (int k = 0; k < 5; ++k) {
                    const int pos = r * NW + 2 * tl + k;
                    const float4 e = *(const float4*)&band[bnd(pos, c4)];
                    s.x += e.x; s.y += e.y; s.z += e.z; s.w += e.w;
                }
            *(float4*)&Sl[tl * 16 + c4 * 4] = s;
        }
        __syncthreads();                       // S ready
        if (dval) {
            float4 sv[4];
            #pragma unroll
            for (int c4 = 0; c4 < 4; ++c4) sv[c4] = *(const float4*)&Sl[tile0 * 16 + c4 * 4];
            #pragma unroll
            for (int c4 = 0; c4 < 4; ++c4) {
                const float4 e = *(const float4*)&band[bnd(pos0, c4)];
                acc0 += e.x * sv[c4].x + e.y * sv[c4].y + e.z * sv[c4].z + e.w * sv[c4].w;
            }
            if (tile1 != tile0) {              // 15 boundary threads only
                #pragma unroll
                for (int c4 = 0; c4 < 4; ++c4) sv[c4] = *(const float4*)&Sl[tile1 * 16 + c4 * 4];
            }
            #pragma unroll
            for (int c4 = 0; c4 < 4; ++c4) {
                const float4 e = *(const float4*)&band[bnd(pos1, c4)];
                acc1 += e.x * sv[c4].x + e.y * sv[c4].y + e.z * sv[c4].z + e.w * sv[c4].w;
            }
        }
    }

    // ---- epilogue: strip max over all 750 items (s >= 0), one atomic ----
    float m = 0.0f;
    if (dval) m = fmaxf(fmaxf(1.0f - acc0 * 0.04f, 1.0f - acc1 * 0.04f), 0.0f);
    #pragma unroll
    for (int off = 1; off < 64; off <<= 1) m = fmaxf(m, __shfl_xor(m, off));
    if ((t & 63) == 0) wmax[t >> 6] = m;
    __syncthreads();
    if (t == 0) {
        #pragma unroll
        for (int i = 1; i < NTHR / 64; ++i) m = fmaxf(m, wmax[i]);
        atomicMax((int*)&tops[b], __float_as_int(m));   // m >= 0, int-pun valid
    }
}

__global__ void finalize(const float* __restrict__ tops,
                         const int* __restrict__ label,
                         float* __restrict__ out) {
    if (threadIdx.x == 0) {
        float fs = 0.0f, rs = 0.0f, fc = 0.0f, rc = 0.0f;
        for (int b = 0; b < NB; ++b) {
            const float tb  = tops[b];
            const float lbv = (float)label[b];
            fs += tb * lbv;          fc += lbv;
            rs += tb * (1.0f - lbv); rc += (1.0f - lbv);
        }
        const float loss = 1.0f - fs / fc + rs / rc;
        out[0] = fmaxf(loss, 0.0f);
    }
}

extern "C" void kernel_launch(void* const* d_in, const int* in_sizes, int n_in,
                              void* d_out, int out_size, void* d_ws, size_t ws_size,
                              hipStream_t stream) {
    const float* feature = (const float*)d_in[0];
    const int* label     = (const int*)d_in[1];
    float* out  = (float*)d_out;
    float* tops = (float*)d_ws;   // 32 floats of scratch

    init_tops<<<1, 64, 0, stream>>>(tops);
    strip_kernel<<<NSTRIP, NTHR, 0, stream>>>(feature, tops);
    finalize<<<1, 64, 0, stream>>>(tops, label, out);
}

// Round 8
// 67.107 us; speedup vs baseline: 17.8957x; 1.2057x over previous
//
#include <hip/hip_runtime.h>

// Problem constants (fixed by reference setup_inputs)
#define NB 32
#define NC 128
#define NH 63
#define NW 63
#define HW (NH*NW)       // 3969
#define OH 30            // (63-5)/2+1
#define OW 30
#define NPOS (5*NW)      // 315 band positions per strip
#define NTILE 30
#define NITEM (NTILE*25) // 750 (tile, p) items
#define NTHR 384
#define NSTRIP (NB*OH)   // 960

// Band row = 16 floats (64B); granule swizzle spreads the 4 float4-slots so
// consecutive positions rotate bank-granules: slot = (c4 + (pos>>1)) & 3.
__device__ __forceinline__ int bnd(int pos, int c4) {
    return pos * 16 + (((c4 + (pos >> 1)) & 3) << 2);
}

__global__ void init_tops(float* tops) {
    if (threadIdx.x < NB) tops[threadIdx.x] = 0.0f;
}

// s[p] = 1 - (1/25) * e_p . S,  e = f/||f||,  S = sum of the tile's 25 e-vectors.
// NOTE: no min-waves clause in launch_bounds — with it, the allocator collapses
// to 32 VGPR and spills the pass-2 live set (R6: 2.6 GB, R7: 58 MB scratch).
__global__ __launch_bounds__(NTHR) void strip_kernel(const float* __restrict__ f,
                                                     float* __restrict__ tops) {
    // XCD-chunked swizzle (bijective: 960 = 8*120): adjacent strips share 3/5 rows.
    const int lb = (blockIdx.x & 7) * (NSTRIP / 8) + (blockIdx.x >> 3);
    const int b  = lb / OH;
    const int oi = lb % OH;
    const int y0 = oi * 2;
    const int t  = threadIdx.x;

    __shared__ __align__(16) float band[NPOS * 16];   // 20.2 KB, normalized chunk
    __shared__ __align__(16) float Sl[NTILE * 16];    // per-tile S (chunk slice)
    __shared__ float wmax[NTHR / 64];

    // ---- staging geometry: thread t<315 owns band position t = (sr, sx) ----
    const bool sval = t < NPOS;
    const int  sr = sval ? t / 63 : 0;
    const int  sx = sval ? t % 63 : 0;
    const float* gp = f + (size_t)b * NC * HW + (size_t)(y0 + sr) * NW + sx;

    // ---- pass 1: per-position sum of squares over all 128 channels (registers) ----
    float sumsq = 0.0f;
    if (sval) {
        const float* p = gp;
        #pragma unroll 16
        for (int c = 0; c < NC; ++c) { const float v = *p; p += HW; sumsq = fmaf(v, v, sumsq); }
    }
    const float inv = (sumsq > 0.0f) ? rsqrtf(sumsq) : 0.0f;

    // ---- dot geometry: thread t<375 owns items 2t, 2t+1 (usually same tile) ----
    const bool dval  = t < (NITEM / 2);
    const int  it0   = 2 * t, it1 = 2 * t + 1;
    const int  tile0 = it0 / 25, p0 = it0 % 25;
    const int  tile1 = it1 / 25, p1 = it1 % 25;
    const int  pos0  = (p0 / 5) * NW + 2 * tile0 + (p0 % 5);
    const int  pos1  = (p1 / 5) * NW + 2 * tile1 + (p1 % 5);
    float acc0 = 0.0f, acc1 = 0.0f;

    // ---- pass 2: 8 channel-chunks of 16 ----
    #pragma unroll 1
    for (int ch = 0; ch < 8; ++ch) {
        __syncthreads();                       // prev chunk's dots done
        if (sval) {
            const float* p = gp + (size_t)(ch * 16) * HW;
            float v[16];
            #pragma unroll
            for (int k = 0; k < 16; ++k) { v[k] = *p; p += HW; }
            #pragma unroll
            for (int c4 = 0; c4 < 4; ++c4) {
                const float4 e = {v[4*c4] * inv, v[4*c4+1] * inv,
                                  v[4*c4+2] * inv, v[4*c4+3] * inv};
                *(float4*)&band[bnd(t, c4)] = e;
            }
        }
        __syncthreads();                       // band ready
        if (t < NTILE * 4) {                   // per-tile window sum S
            const int tl = t >> 2, c4 = t & 3;
            float4 s = {0.0f, 0.0f, 0.0f, 0.0f};
            #pragma unroll
            for (int r = 0; r < 5; ++r)
                #pragma unroll
                for (int k = 0; k < 5; ++k) {
                    const int pos = r * NW + 2 * tl + k;
                    const float4 e = *(const float4*)&band[bnd(pos, c4)];
                    s.x += e.x; s.y += e.y; s.z += e.z; s.w += e.w;
                }
            *(float4*)&Sl[tl * 16 + c4 * 4] = s;
        }
        __syncthreads();                       // S ready
        if (dval) {
            float4 sv[4];
            #pragma unroll
            for (int c4 = 0; c4 < 4; ++c4) sv[c4] = *(const float4*)&Sl[tile0 * 16 + c4 * 4];
            #pragma unroll
            for (int c4 = 0; c4 < 4; ++c4) {
                const float4 e = *(const float4*)&band[bnd(pos0, c4)];
                acc0 += e.x * sv[c4].x + e.y * sv[c4].y + e.z * sv[c4].z + e.w * sv[c4].w;
            }
            if (tile1 != tile0) {              // 15 boundary threads only
                #pragma unroll
                for (int c4 = 0; c4 < 4; ++c4) sv[c4] = *(const float4*)&Sl[tile1 * 16 + c4 * 4];
            }
            #pragma unroll
            for (int c4 = 0; c4 < 4; ++c4) {
                const float4 e = *(const float4*)&band[bnd(pos1, c4)];
                acc1 += e.x * sv[c4].x + e.y * sv[c4].y + e.z * sv[c4].z + e.w * sv[c4].w;
            }
        }
    }

    // ---- epilogue: strip max over all 750 items (s >= 0), one atomic ----
    float m = 0.0f;
    if (dval) m = fmaxf(fmaxf(1.0f - acc0 * 0.04f, 1.0f - acc1 * 0.04f), 0.0f);
    #pragma unroll
    for (int off = 1; off < 64; off <<= 1) m = fmaxf(m, __shfl_xor(m, off));
    if ((t & 63) == 0) wmax[t >> 6] = m;
    __syncthreads();
    if (t == 0) {
        #pragma unroll
        for (int i = 1; i < NTHR / 64; ++i) m = fmaxf(m, wmax[i]);
        atomicMax((int*)&tops[b], __float_as_int(m));   // m >= 0, int-pun valid
    }
}

__global__ void finalize(const float* __restrict__ tops,
                         const int* __restrict__ label,
                         float* __restrict__ out) {
    if (threadIdx.x == 0) {
        float fs = 0.0f, rs = 0.0f, fc = 0.0f, rc = 0.0f;
        for (int b = 0; b < NB; ++b) {
            const float tb  = tops[b];
            const float lbv = (float)label[b];
            fs += tb * lbv;          fc += lbv;
            rs += tb * (1.0f - lbv); rc += (1.0f - lbv);
        }
        const float loss = 1.0f - fs / fc + rs / rc;
        out[0] = fmaxf(loss, 0.0f);
    }
}

extern "C" void kernel_launch(void* const* d_in, const int* in_sizes, int n_in,
                              void* d_out, int out_size, void* d_ws, size_t ws_size,
                              hipStream_t stream) {
    const float* feature = (const float*)d_in[0];
    const int* label     = (const int*)d_in[1];
    float* out  = (float*)d_out;
    float* tops = (float*)d_ws;   // 32 floats of scratch

    init_tops<<<1, 64, 0, stream>>>(tops);
    strip_kernel<<<NSTRIP, NTHR, 0, stream>>>(feature, tops);
    finalize<<<1, 64, 0, stream>>>(tops, label, out);
}